// Round 8
// baseline (346.222 us; speedup 1.0000x reference)
//
#include <hip/hip_runtime.h>
#include <stdint.h>

#define B_DIM 8192
#define DIN   2048
#define DOUT  8192
#define NKT   (DIN / 128)  // 16 K-tiles of 128 bytes

typedef int  v4i __attribute__((ext_vector_type(4)));
typedef char c8  __attribute__((ext_vector_type(8)));

__device__ __forceinline__ void gload_lds16(const void* g, void* l) {
  __builtin_amdgcn_global_load_lds(
      (const __attribute__((address_space(1))) void*)g,
      (__attribute__((address_space(3))) void*)l, 16, 0, 0);
}

__device__ __forceinline__ float wave_max(float m) {
#pragma unroll
  for (int off = 32; off; off >>= 1) m = fmaxf(m, __shfl_xor(m, off, 64));
  return m;
}

// ---- kernel 0: zero the two atomic absmax words ----
__global__ void k_init(unsigned int* p) {
  p[0] = 0u;
  p[1] = 0u;
}

// ---- kernel 1: global absmax of x (block-reduced, 1 atomic/block) ----
__global__ __launch_bounds__(256) void k_absmax(const float4* __restrict__ x,
                                                int n4,
                                                unsigned int* __restrict__ out_bits) {
  int idx = blockIdx.x * blockDim.x + threadIdx.x;
  int stride = gridDim.x * blockDim.x;
  float m = 0.f;
  for (int i = idx; i < n4; i += stride) {
    float4 v = x[i];
    m = fmaxf(m, fabsf(v.x));
    m = fmaxf(m, fabsf(v.y));
    m = fmaxf(m, fabsf(v.z));
    m = fmaxf(m, fabsf(v.w));
  }
  m = wave_max(m);
  __shared__ float red[4];
  if ((threadIdx.x & 63) == 0) red[threadIdx.x >> 6] = m;
  __syncthreads();
  if (threadIdx.x == 0) {
    m = fmaxf(fmaxf(red[0], red[1]), fmaxf(red[2], red[3]));
    atomicMax(out_bits, __float_as_uint(m));
  }
}

// ---- kernel 2: quantize x to int8 (8 elems/thread) ----
__global__ void k_quant_x(const float* __restrict__ x, c8* __restrict__ xq,
                          int n8, const unsigned int* __restrict__ sa_bits) {
  int i = blockIdx.x * blockDim.x + threadIdx.x;
  if (i >= n8) return;
  float s_a = __uint_as_float(*sa_bits) / 127.0f;
  const float4* p = (const float4*)(x + (size_t)i * 8);
  float4 v0 = p[0], v1 = p[1];
  float vv[8] = {v0.x, v0.y, v0.z, v0.w, v1.x, v1.y, v1.z, v1.w};
  c8 q;
#pragma unroll
  for (int j = 0; j < 8; ++j) {
    float r = fminf(fmaxf(rintf(vv[j] / s_a), -127.f), 127.f);
    q[j] = (char)(int)r;
  }
  xq[i] = q;
}

// ---- kernel 3: per-row weight absmax + quantize (1 block / row) ----
__global__ __launch_bounds__(256) void k_quant_w(const float* __restrict__ w,
                                                 c8* __restrict__ wq,
                                                 float* __restrict__ s_w) {
  int row = blockIdx.x;
  int tid = threadIdx.x;
  const float4* wr = (const float4*)(w + (size_t)row * DIN);
  float4 v0 = wr[tid * 2], v1 = wr[tid * 2 + 1];
  float vv[8] = {v0.x, v0.y, v0.z, v0.w, v1.x, v1.y, v1.z, v1.w};
  float m = 0.f;
#pragma unroll
  for (int j = 0; j < 8; ++j) m = fmaxf(m, fabsf(vv[j]));
  m = wave_max(m);
  __shared__ float wmax[4];
  if ((tid & 63) == 0) wmax[tid >> 6] = m;
  __syncthreads();
  m = fmaxf(fmaxf(wmax[0], wmax[1]), fmaxf(wmax[2], wmax[3]));
  float s = m / 127.0f;
  if (tid == 0) s_w[row] = s;
  c8 q;
#pragma unroll
  for (int j = 0; j < 8; ++j) {
    float r = fminf(fmaxf(rintf(vv[j] / s), -127.f), 127.f);
    q[j] = (char)(int)r;
  }
  wq[(size_t)row * (DIN / 8) + tid] = q;
}

// ---- kernel 4: int8 GEMM, 256x256, 8-phase, compiler-scheduled lgkm ----
// Identical memory map / stage calendar / barrier count to R7 (verified):
// regions (slot,op,ks) 16KB, [rblk16][kg4][fr16] cells, 0-conflict frag
// reads; stage calendar p1:A1(t1) p2:B0(t2) p3:A0(t2) p4:B1(t2)+v6
// p5:A1(t2) p6:B0(t3) p7:A0(t3) p8:B1(t3)+v6; 2D XCD patch swizzle.
// R8 change: NO full lgkmcnt(0) drain before MFMAs. Compiler emits precise
// per-MFMA lgkmcnt(N) -> early MFMAs overlap late ds_reads (m97/m141
// evidence: full drains serialize read-burst then MFMA-burst = the measured
// 29% wall). Hazard guarantee kept: every read is consumed by an MFMA above
// sched_barrier(0)+barrier#2 (in-order lgkm => wave drained before passing
// barrier#2; restages issue post-barrier#2 => no DMA-vs-pending-read race).
__global__ __launch_bounds__(512, 2) void k_gemm8(
    const char* __restrict__ Aq, const char* __restrict__ Bq,
    const float* __restrict__ s_w, const float* __restrict__ bias,
    const unsigned int* __restrict__ sa_bits, float* __restrict__ out,
    unsigned int* __restrict__ omax_bits) {
  __shared__ __align__(16) char lds[131072];

  const int tid = threadIdx.x;
  const int lane = tid & 63;
  const int wave = tid >> 6;
  const int wm = wave >> 2;  // 0..1 (M)
  const int wn = wave & 3;   // 0..3 (N)

  // bijective 2D L2-patch swizzle (R4-verified: FETCH 271->99 MB)
  const int orig = blockIdx.x;
  const int xcd = orig & 7;
  const int k = orig >> 3;
  const int bx = (xcd & 3) * 8 + (k & 7);
  const int by = (xcd >> 2) * 16 + (k >> 3);
  const int row0 = by * 256, col0 = bx * 256;

  // staging source mapping: thread t -> cell (rblk=t>>6, kg=(t>>4)&3, fr=t&15)
  const int srow = ((tid >> 6) << 4) | (tid & 15);
  const int skb = tid & 48;
  const char* aS = Aq + (size_t)(row0 + srow) * DIN + skb;
  const char* bS = Bq + (size_t)(col0 + srow) * DIN + skb;

  // stage one (op,ks) region of K-tile kt into slot kt&1 (2 gloads)
  auto STAGE = [&](int kt, int isB, int ks) {
    if (kt >= NKT) kt -= 2;  // tail: same slot, same bytes
    const int slot = kt & 1;
    const char* src = (isB ? bS : aS) + (size_t)kt * 128 + ks * 64;
    const int dst = slot * 65536 + isB * 32768 + ks * 16384 + tid * 16;
    gload_lds16(src, &lds[dst]);
    gload_lds16(src + (size_t)128 * DIN, &lds[dst + 8192]);
  };

  v4i acc[2][4][4];
#pragma unroll
  for (int mh = 0; mh < 2; ++mh)
#pragma unroll
    for (int mf = 0; mf < 4; ++mf)
#pragma unroll
      for (int nf = 0; nf < 4; ++nf) acc[mh][mf][nf] = (v4i){0, 0, 0, 0};

  const int lb = lane * 16;
  v4i b_[4];  // persists across the (mh0, mh1) phase pair

#define PH(SLOT, KS, MH, SKT, SISB, SKS, WAITV)                              \
  do {                                                                       \
    v4i a_[4];                                                               \
    const int ab =                                                           \
        (SLOT) * 65536 + (KS) * 16384 + (wm * 8 + (MH) * 4) * 1024 + lb;     \
    const int bb =                                                           \
        (SLOT) * 65536 + 32768 + (KS) * 16384 + (wn * 4) * 1024 + lb;        \
    /* read order: b0, a0..a3, b1..b3 -> first MFMAs need first reads */     \
    if (!(MH)) b_[0] = *(const v4i*)&lds[bb];                                \
    _Pragma("unroll") for (int mf = 0; mf < 4; ++mf) a_[mf] =                \
        *(const v4i*)&lds[ab + mf * 1024];                                   \
    if (!(MH)) {                                                             \
      _Pragma("unroll") for (int nf = 1; nf < 4; ++nf) b_[nf] =              \
          *(const v4i*)&lds[bb + nf * 1024];                                 \
    }                                                                        \
    STAGE(SKT, SISB, SKS);                                                   \
    if (WAITV) asm volatile("s_waitcnt vmcnt(6)" ::: "memory");              \
    asm volatile("s_barrier" ::: "memory");                                  \
    __builtin_amdgcn_s_setprio(1);                                           \
    _Pragma("unroll") for (int nf = 0; nf < 4; ++nf)                         \
        _Pragma("unroll") for (int mf = 0; mf < 4; ++mf) acc[MH][mf][nf] =   \
        __builtin_amdgcn_mfma_i32_16x16x64_i8(a_[mf], b_[nf],                \
                                              acc[MH][mf][nf], 0, 0, 0);     \
    __builtin_amdgcn_s_setprio(0);                                           \
    __builtin_amdgcn_sched_barrier(0);                                       \
    asm volatile("s_barrier" ::: "memory");                                  \
  } while (0)

  // prologue: t0 fully (4 units), t1 minus A1 (issued, unconfirmed);
  // vmcnt(6) confirms exactly t0's 8 loads (14 outstanding -> keep 6).
  STAGE(0, 1, 0);  // t0 B0
  STAGE(0, 0, 0);  // t0 A0
  STAGE(0, 1, 1);  // t0 B1
  STAGE(0, 0, 1);  // t0 A1
  STAGE(1, 1, 0);  // t1 B0
  STAGE(1, 0, 0);  // t1 A0
  STAGE(1, 1, 1);  // t1 B1
  asm volatile("s_waitcnt vmcnt(6)" ::: "memory");
  asm volatile("s_barrier" ::: "memory");

#pragma unroll 1
  for (int i = 0; i < NKT / 2; ++i) {
    const int t1 = 2 * i + 1, t2 = 2 * i + 2, t3 = 2 * i + 3;
    PH(0, 0, 0, t1, 0, 1, false);  // p1: stage A1(t1)
    PH(0, 0, 1, t2, 1, 0, false);  // p2: stage B0(t2)
    PH(0, 1, 0, t2, 0, 0, false);  // p3: stage A0(t2)
    PH(0, 1, 1, t2, 1, 1, true);   // p4: stage B1(t2), vmcnt(6)
    PH(1, 0, 0, t2, 0, 1, false);  // p5: stage A1(t2)
    PH(1, 0, 1, t3, 1, 0, false);  // p6: stage B0(t3)
    PH(1, 1, 0, t3, 0, 0, false);  // p7: stage A0(t3)
    PH(1, 1, 1, t3, 1, 1, true);   // p8: stage B1(t3), vmcnt(6)
  }
#undef PH

  // epilogue: out = (acc + round(bias/s_b)) * s_b, s_b = s_w[col]*s_a
  const int fr = lane & 15;
  float s_a = __uint_as_float(*sa_bits) / 127.0f;
  float lmax = 0.f;
#pragma unroll
  for (int nf = 0; nf < 4; ++nf) {
    int col = col0 + wn * 64 + nf * 16 + fr;
    float sw = s_w[col];
    float sb = sw * s_a;
    float bint = rintf(bias[col] / sb);
#pragma unroll
    for (int mh = 0; mh < 2; ++mh)
#pragma unroll
      for (int mf = 0; mf < 4; ++mf) {
        int rbase = row0 + wm * 128 + mh * 64 + mf * 16 + (lane >> 4) * 4;
#pragma unroll
        for (int r = 0; r < 4; ++r) {
          float o = ((float)acc[mh][mf][nf][r] + bint) * sb;
          out[(size_t)(rbase + r) * DOUT + col] = o;
          lmax = fmaxf(lmax, fabsf(o));
        }
      }
  }
  // block-level max reduce -> 1 atomic per block
  lmax = wave_max(lmax);
  asm volatile("s_waitcnt vmcnt(0)" ::: "memory");  // drain tail DMA into LDS
  __syncthreads();
  float* red = (float*)lds;
  if (lane == 0) red[wave] = lmax;
  __syncthreads();
  if (tid == 0) {
    float m = 0.f;
#pragma unroll
    for (int w2 = 0; w2 < 8; ++w2) m = fmaxf(m, red[w2]);
    atomicMax(omax_bits, __float_as_uint(m));
  }
}

// ---- kernel 5: requantize output in place ----
__global__ void k_requant(float4* __restrict__ out, int n4,
                          const unsigned int* __restrict__ omax_bits) {
  float s_o = __uint_as_float(*omax_bits) / 127.0f;
  int idx = blockIdx.x * blockDim.x + threadIdx.x;
  int stride = gridDim.x * blockDim.x;
  for (int i = idx; i < n4; i += stride) {
    float4 v = out[i];
    v.x = fminf(fmaxf(rintf(v.x / s_o), -127.f), 127.f) * s_o;
    v.y = fminf(fmaxf(rintf(v.y / s_o), -127.f), 127.f) * s_o;
    v.z = fminf(fmaxf(rintf(v.z / s_o), -127.f), 127.f) * s_o;
    v.w = fminf(fmaxf(rintf(v.w / s_o), -127.f), 127.f) * s_o;
    out[i] = v;
  }
}

extern "C" void kernel_launch(void* const* d_in, const int* in_sizes, int n_in,
                              void* d_out, int out_size, void* d_ws,
                              size_t ws_size, hipStream_t stream) {
  const float* x = (const float*)d_in[0];
  const float* w = (const float*)d_in[1];
  const float* bias = (const float*)d_in[2];
  float* out = (float*)d_out;
  char* ws = (char*)d_ws;

  unsigned int* absbits = (unsigned int*)ws;
  float* s_w = (float*)(ws + 512);
  char* xq = ws + 65536;
  char* wq = ws + 65536 + (size_t)B_DIM * DIN;

  k_init<<<1, 1, 0, stream>>>(absbits);
  k_absmax<<<1024, 256, 0, stream>>>((const float4*)x, B_DIM * DIN / 4, absbits);
  k_quant_x<<<(B_DIM * DIN / 8) / 256, 256, 0, stream>>>(x, (c8*)xq,
                                                         B_DIM * DIN / 8, absbits);
  k_quant_w<<<DOUT, 256, 0, stream>>>(w, (c8*)wq, s_w);
  k_gemm8<<<1024, 512, 0, stream>>>(xq, wq, s_w, bias, absbits, out, absbits + 1);
  k_requant<<<4096, 256, 0, stream>>>((float4*)out, B_DIM * DOUT / 4, absbits + 1);
}